// Round 5
// baseline (325.635 us; speedup 1.0000x reference)
//
#include <hip/hip_runtime.h>

using u16 = unsigned short;
using u64 = unsigned long long;

// Problem constants (fixed by reference)
constexpr int BATCH = 64, SEQ = 1024, FEAT = 512, NBINS = 32;
constexpr int N = BATCH * SEQ;              // 65536 samples
constexpr int TAB = 131072;                 // hash table slots (2N), pow2
constexpr unsigned TABMASK = TAB - 1;
constexpr u64 EMPTY = ~0ull;                // combined <= 2^32-1, safe sentinel
constexpr double FXSCALE = 67108864.0;      // 2^26 fixed-point for stat atomics

// NOTE (R4 post-mortem): the JAX reference under default config runs int64 as
// int32; left_shift(env, 32) on int32 is 0 in XLA, so the reference's
// combined id is the 32-bit key ONLY (env dropped). We replicate that.

// Workspace layout (bytes)
constexpr size_t OFF_KEYS = 0;              // u64[TAB]   1048576 (memset 0xFF)
constexpr size_t OFF_HEAD = 1048576;        // i32[TAB]   524288  (memset 0xFF -> -1)
constexpr size_t OFF_CNT = 1572864;         // u32[TAB]   524288  (memset 0x00)
constexpr size_t OFF_ISUMS = 2097152;       // i64[512]   4096    (memset 0x00)
constexpr size_t OFF_ISUMSQ = 2101248;      // i64[512]   4096    (memset 0x00)
constexpr size_t OFF_QD = 2105344;          // f64[16384] 131072
constexpr size_t OFF_CD = 2236416;          // f64[32]    256
constexpr size_t OFF_SLOT = 2236672;        // i32[N]     262144
constexpr size_t OFF_NEXT = 2498816;        // i32[N]     262144
// total 2760960 bytes

// ---------------- Kernel A: per-column sum / sumsq of f32 input
// (fp64 regs, deterministic int fixed-point atomics)
__global__ __launch_bounds__(256) void colstats_kernel(
    const float4* __restrict__ xv,  // f32 features, 8388608 float4s
    u64* __restrict__ isums, u64* __restrict__ isumsq) {
  const int t = threadIdx.x;
  const int gid = blockIdx.x * 256 + t;  // 512 blocks * 256 = 131072 threads
  double s0 = 0, s1 = 0, s2 = 0, s3 = 0, q0 = 0, q1 = 0, q2 = 0, q3 = 0;
#pragma unroll 8
  for (int k = 0; k < 64; k++) {
    float4 v = xv[gid + k * 131072];
    double a = (double)v.x, b = (double)v.y, c = (double)v.z, d = (double)v.w;
    s0 += a; s1 += b; s2 += c; s3 += d;
    q0 += a * a; q1 += b * b; q2 += c * c; q3 += d * d;
  }
  __shared__ double red[256 * 8];
  red[t * 8 + 0] = s0; red[t * 8 + 1] = s1; red[t * 8 + 2] = s2; red[t * 8 + 3] = s3;
  red[t * 8 + 4] = q0; red[t * 8 + 5] = q1; red[t * 8 + 6] = q2; red[t * 8 + 7] = q3;
  __syncthreads();
  if (t < 128) {
    // threads t and t+128 own the same 4 columns (gid mod 128 == t mod 128)
    double v[8];
#pragma unroll
    for (int u = 0; u < 8; u++) v[u] = red[t * 8 + u] + red[(t + 128) * 8 + u];
    const int c0 = 4 * t;
#pragma unroll
    for (int u = 0; u < 4; u++) {
      long long a = (long long)llrint(v[u] * FXSCALE);
      long long b = (long long)llrint(v[4 + u] * FXSCALE);
      atomicAdd(&isums[c0 + u], (u64)a);
      atomicAdd(&isumsq[c0 + u], (u64)b);
    }
  }
}

// ---------------- Kernel B: finalize mean/inv-sigma (f64), Qd = P/sigma,
// cd[j] = sum_f mean_f * Qd[f][j], deterministic reduction order.
__global__ __launch_bounds__(512) void finalize_kernel(
    const float* __restrict__ P,  // f32 [512][32]
    const u64* __restrict__ isums, const u64* __restrict__ isumsq,
    double* __restrict__ Qd, double* __restrict__ cd) {
  __shared__ double meanArr[FEAT];
  __shared__ double invArr[FEAT];
  __shared__ double part[16][NBINS];
  const int t = threadIdx.x;  // t = feature index, 512 threads
  const double Nd = (double)N;
  const double tot = 1e-4 + Nd;
  double s = (double)(long long)isums[t] * (1.0 / FXSCALE);
  double ss = (double)(long long)isumsq[t] * (1.0 / FXSCALE);
  double bm = s / Nd;
  double bv = (ss - s * s / Nd) / (Nd - 1.0);  // unbiased var
  double mean = bm * Nd / tot;
  double M2 = 1e-4 + bv * Nd + bm * bm * 1e-4 * Nd / tot;
  double var = M2 / tot;
  double inv = 1.0 / sqrt(var + 1e-8);
  meanArr[t] = mean;
  invArr[t] = inv;
#pragma unroll
  for (int j = 0; j < NBINS; j++) {
    Qd[t * NBINS + j] = (double)P[t * NBINS + j] * inv;
  }
  __syncthreads();
  // c reduction: thread t handles bin j=t&31, feature block g=t>>5 (32 feats)
  {
    const int j = t & 31, g = t >> 5;
    double p = 0.0;
    for (int f = g * 32; f < g * 32 + 32; f++) {
      double qd = (double)P[f * NBINS + j] * invArr[f];
      p += meanArr[f] * qd;
    }
    part[g][j] = p;
  }
  __syncthreads();
  if (t < NBINS) {
    double c = 0.0;
    for (int g = 0; g < 16; g++) c += part[g][t];  // fixed order -> deterministic
    cd[t] = c;
  }
}

// ---------------- Kernel C: per-sample key bits (f64 dot products) + hash insert
// 1024 blocks x 256 threads; block = 64 rows; wave w handles bins 8w..8w+7, lane = row
__global__ __launch_bounds__(256) void project_kernel(
    const float4* __restrict__ xv,
    const double* __restrict__ Qd, const double* __restrict__ cd,
    u64* __restrict__ keys_tab, int* __restrict__ head,
    unsigned* __restrict__ cnt, int* __restrict__ slot, int* __restrict__ nxt) {
  __shared__ __align__(16) float xt[64 * 132];  // 64 rows x 128 floats, stride 132
  __shared__ unsigned keyParts[64];
  const int t = threadIdx.x;
  const int rowBase = blockIdx.x * 64;
  const int lane = t & 63;
  const int wid = t >> 6;
  const int j0 = __builtin_amdgcn_readfirstlane(wid * 8);  // uniform -> scalar Qd loads
  if (t < 64) keyParts[t] = 0u;

  double acc[8] = {0, 0, 0, 0, 0, 0, 0, 0};
  for (int ch = 0; ch < 4; ch++) {  // feature chunks of 128
    __syncthreads();                // protects keyParts init / xt reuse
#pragma unroll
    for (int k = 0; k < 8; k++) {   // stage 64 rows x 32 float4
      int vi = t + k * 256;
      int r = vi >> 5, fv = vi & 31;
      float4 v = xv[(size_t)(rowBase + r) * 128 + ch * 32 + fv];
      *((float4*)&xt[r * 132 + fv * 4]) = v;
    }
    __syncthreads();
    const double* qbase = Qd + ch * 128 * NBINS + j0;
    const float4* xrow = (const float4*)&xt[lane * 132];
#pragma unroll 4
    for (int g = 0; g < 32; g++) {
      float4 x4 = xrow[g];
      double dx = (double)x4.x, dy = (double)x4.y, dz = (double)x4.z, dw = (double)x4.w;
      const double* qp = qbase + g * 4 * NBINS;
#pragma unroll
      for (int j = 0; j < 8; j++) {
        double a = acc[j];
        a = fma(dx, qp[j], a);
        a = fma(dy, qp[NBINS + j], a);
        a = fma(dz, qp[2 * NBINS + j], a);
        a = fma(dw, qp[3 * NBINS + j], a);
        acc[j] = a;
      }
    }
  }
  unsigned part = 0;
#pragma unroll
  for (int j = 0; j < 8; j++) {
    if (acc[j] > cd[j0 + j]) part |= (1u << (j0 + j));
  }
  atomicOr(&keyParts[lane], part);
  __syncthreads();
  if (t < 64) {
    const int i = rowBase + t;
    unsigned key = keyParts[t];
    // Reference (JAX int32 semantics): env<<32 vanishes -> id is the key only.
    u64 combined = (u64)key;
    unsigned idx = (unsigned)((combined * 0x9E3779B97F4A7C15ull) >> 47) & TABMASK;
    for (;;) {
      u64 prev = atomicCAS(&keys_tab[idx], EMPTY, combined);
      if (prev == EMPTY || prev == combined) break;
      idx = (idx + 1) & TABMASK;
    }
    slot[i] = (int)idx;
    atomicAdd(&cnt[idx], 1u);
    nxt[i] = atomicExch(&head[idx], i);
  }
}

// ---------------- Kernel D: occurrence rank -> reward (order-independent)
__global__ __launch_bounds__(256) void count_kernel(
    const int* __restrict__ slot, const int* __restrict__ nxt,
    const int* __restrict__ head, const unsigned* __restrict__ cnt,
    float* __restrict__ out) {
  const int i = blockIdx.x * 256 + threadIdx.x;
  const int sl = slot[i];
  const unsigned c = cnt[sl];
  float r = 1.0f;
  if (c > 1u) {
    int j = head[sl];
    int occ = 1;
    while (j >= 0) {
      occ += (j < i) ? 1 : 0;
      j = nxt[j];
    }
    r = 1.0f / sqrtf((float)occ);
  }
  out[i] = r;
}

extern "C" void kernel_launch(void* const* d_in, const int* in_sizes, int n_in,
                              void* d_out, int out_size, void* d_ws, size_t ws_size,
                              hipStream_t stream) {
  const float4* xv = (const float4*)d_in[0];  // features f32 [64*1024][512]
  const float* proj = (const float*)d_in[1];  // random_projection f32 [512][32]
  float* out = (float*)d_out;                 // [65536] f32
  char* ws = (char*)d_ws;

  u64* keys_tab = (u64*)(ws + OFF_KEYS);
  int* head = (int*)(ws + OFF_HEAD);
  unsigned* cnt = (unsigned*)(ws + OFF_CNT);
  u64* isums = (u64*)(ws + OFF_ISUMS);
  u64* isumsq = (u64*)(ws + OFF_ISUMSQ);
  double* Qd = (double*)(ws + OFF_QD);
  double* cd = (double*)(ws + OFF_CD);
  int* slot = (int*)(ws + OFF_SLOT);
  int* nxt = (int*)(ws + OFF_NEXT);

  // init: keys_tab + head -> 0xFF (EMPTY / -1); cnt + isums + isumsq -> 0
  hipMemsetAsync(ws + OFF_KEYS, 0xFF, OFF_CNT - OFF_KEYS, stream);
  hipMemsetAsync(ws + OFF_CNT, 0x00, OFF_QD - OFF_CNT, stream);

  colstats_kernel<<<512, 256, 0, stream>>>(xv, isums, isumsq);
  finalize_kernel<<<1, 512, 0, stream>>>(proj, isums, isumsq, Qd, cd);
  project_kernel<<<N / 64, 256, 0, stream>>>(xv, Qd, cd, keys_tab, head, cnt, slot, nxt);
  count_kernel<<<N / 256, 256, 0, stream>>>(slot, nxt, head, cnt, out);
}